// Round 1
// baseline (4806.667 us; speedup 1.0000x reference)
//
#include <hip/hip_runtime.h>

#define NB   512   // batch
#define NT   256   // time steps
#define NI   32    // input dim
#define NH   128   // hidden
#define NG   512   // 4*NH gates

__device__ __forceinline__ float fast_sigmoid(float x) {
    return 1.0f / (1.0f + __expf(-x));
}
__device__ __forceinline__ float fast_tanh(float x) {
    float ax = fabsf(x);
    float e  = __expf(-2.0f * ax);
    float t  = (1.0f - e) / (1.0f + e);
    return copysignf(t, x);
}
__device__ __forceinline__ float gate_act(float x, int g) {
    // gate order from jnp.split: i[0:128] f[128:256] g[256:384] o[384:512]
    return (g >= 256 && g < 384) ? fast_tanh(x) : fast_sigmoid(x);
}

// ---------------------------------------------------------------------------
// Layer-0 LSTM over a chunk of timesteps.
// grid 256 blocks, block 512 threads. Block handles batches {blk, blk+256}.
// Thread g owns gate row g: w_hh0[g,:] (128 VGPRs) + w_ih0[g,:] (32 VGPRs).
// ---------------------------------------------------------------------------
__global__ __launch_bounds__(512, 2)
void lstm0_chunk(const float* __restrict__ x,
                 const float* __restrict__ w_ih, const float* __restrict__ w_hh,
                 const float* __restrict__ b_ih, const float* __restrict__ b_hh,
                 float* __restrict__ h0_buf,                  // [NB][Tc][NH]
                 float* __restrict__ h_state, float* __restrict__ c_state, // [NB][NH]
                 int t0, int Tc, int first)
{
    __shared__ __align__(16) float h_lds[2][NH];
    __shared__ float act_lds[2][NG];
    __shared__ __align__(16) float xs[2][NI];

    const int tid = threadIdx.x;
    const int g   = tid;
    const int blk = blockIdx.x;

    float4 w4[32];
    const float4* wp = (const float4*)(w_hh + (size_t)g * NH);
#pragma unroll
    for (int q = 0; q < 32; ++q) w4[q] = wp[q];
    float4 wi4[8];
    const float4* wip = (const float4*)(w_ih + (size_t)g * NI);
#pragma unroll
    for (int q = 0; q < 8; ++q) wi4[q] = wip[q];
    const float bsum = b_ih[g] + b_hh[g];

    float c_reg = 0.0f, h_keep = 0.0f;
    if (tid < 256) {
        int bb = tid >> 7, j = tid & 127;
        int b  = blk + bb * 256;
        float h = 0.0f;
        if (!first) { h = h_state[b * NH + j]; c_reg = c_state[b * NH + j]; }
        h_lds[bb][j] = h;
        h_keep = h;
    }

    for (int tl = 0; tl < Tc; ++tl) {
        int t = t0 + tl;
        if (tid < 64) {
            int bb = tid >> 5, i = tid & 31;
            int b  = blk + bb * 256;
            xs[bb][i] = x[(size_t)b * (NT * NI) + (size_t)t * NI + i];
        }
        __syncthreads();   // orders: prev update h_lds writes + xs writes  vs  dot reads

        float p0a = bsum, p0b = 0.f, p1a = bsum, p1b = 0.f;
        const float4* h40 = (const float4*)h_lds[0];
        const float4* h41 = (const float4*)h_lds[1];
        const float4* x40 = (const float4*)xs[0];
        const float4* x41 = (const float4*)xs[1];
#pragma unroll
        for (int q = 0; q < 8; ++q) {
            float4 a = x40[q], b2 = x41[q], w = wi4[q];
            p0a += w.x * a.x  + w.y * a.y;   p0b += w.z * a.z  + w.w * a.w;
            p1a += w.x * b2.x + w.y * b2.y;  p1b += w.z * b2.z + w.w * b2.w;
        }
#pragma unroll
        for (int q = 0; q < 32; ++q) {
            float4 h0v = h40[q], h1v = h41[q], w = w4[q];
            p0a += w.x * h0v.x + w.y * h0v.y;  p0b += w.z * h0v.z + w.w * h0v.w;
            p1a += w.x * h1v.x + w.y * h1v.y;  p1b += w.z * h1v.z + w.w * h1v.w;
        }
        act_lds[0][g] = gate_act(p0a + p0b, g);
        act_lds[1][g] = gate_act(p1a + p1b, g);
        __syncthreads();   // orders: act writes vs update reads

        if (tid < 256) {
            int bb = tid >> 7, j = tid & 127;
            int b  = blk + bb * 256;
            float gi = act_lds[bb][j];
            float gf = act_lds[bb][j + 128];
            float gg = act_lds[bb][j + 256];
            float go = act_lds[bb][j + 384];
            c_reg = gf * c_reg + gi * gg;
            float hn = go * fast_tanh(c_reg);
            h_lds[bb][j] = hn;
            h_keep = hn;
            h0_buf[((size_t)b * Tc + tl) * NH + j] = hn;
        }
    }

    if (tid < 256) {
        int bb = tid >> 7, j = tid & 127;
        int b  = blk + bb * 256;
        h_state[b * NH + j] = h_keep;
        c_state[b * NH + j] = c_reg;
    }
}

// ---------------------------------------------------------------------------
// xg1 = h0 @ w_ih1^T + (b_ih1 + b_hh1).  A: [M][128], Wt: [512][128], C: [M][512]
// 64x64 tile / block, 4x4 micro-tile, K=128 staged once (transposed, padded).
// ---------------------------------------------------------------------------
__global__ __launch_bounds__(256)
void xg_gemm(const float* __restrict__ A,
             const float* __restrict__ Wt,
             const float* __restrict__ b_ih, const float* __restrict__ b_hh,
             float* __restrict__ Cout, int M)
{
    __shared__ __align__(16) float As[128][68];
    __shared__ __align__(16) float Bs[128][68];
    const int tid = threadIdx.x;
    const int m0 = blockIdx.x * 64;
    const int n0 = blockIdx.y * 64;

    {
        const float4* srcA = (const float4*)(A + (size_t)m0 * 128);
        const float4* srcB = (const float4*)(Wt + (size_t)n0 * 128);
#pragma unroll
        for (int r = 0; r < 8; ++r) {
            int lin = tid + 256 * r;
            int row = lin >> 5, kq = lin & 31;
            float4 v = srcA[(size_t)row * 32 + kq];
            int k = kq * 4;
            As[k][row] = v.x; As[k + 1][row] = v.y; As[k + 2][row] = v.z; As[k + 3][row] = v.w;
            float4 u = srcB[(size_t)row * 32 + kq];
            Bs[k][row] = u.x; Bs[k + 1][row] = u.y; Bs[k + 2][row] = u.z; Bs[k + 3][row] = u.w;
        }
    }
    __syncthreads();

    const int tx = tid & 15, ty = tid >> 4;
    float acc[4][4] = {};
#pragma unroll 16
    for (int k = 0; k < 128; ++k) {
        float4 a = *(const float4*)&As[k][ty * 4];
        float4 b = *(const float4*)&Bs[k][tx * 4];
        acc[0][0] += a.x * b.x; acc[0][1] += a.x * b.y; acc[0][2] += a.x * b.z; acc[0][3] += a.x * b.w;
        acc[1][0] += a.y * b.x; acc[1][1] += a.y * b.y; acc[1][2] += a.y * b.z; acc[1][3] += a.y * b.w;
        acc[2][0] += a.z * b.x; acc[2][1] += a.z * b.y; acc[2][2] += a.z * b.z; acc[2][3] += a.z * b.w;
        acc[3][0] += a.w * b.x; acc[3][1] += a.w * b.y; acc[3][2] += a.w * b.z; acc[3][3] += a.w * b.w;
    }

    int gb = n0 + tx * 4;
    float4 bias;
    bias.x = b_ih[gb + 0] + b_hh[gb + 0];
    bias.y = b_ih[gb + 1] + b_hh[gb + 1];
    bias.z = b_ih[gb + 2] + b_hh[gb + 2];
    bias.w = b_ih[gb + 3] + b_hh[gb + 3];
#pragma unroll
    for (int i2 = 0; i2 < 4; ++i2) {
        int m = m0 + ty * 4 + i2;
        float4 o;
        o.x = acc[i2][0] + bias.x; o.y = acc[i2][1] + bias.y;
        o.z = acc[i2][2] + bias.z; o.w = acc[i2][3] + bias.w;
        *(float4*)&Cout[(size_t)m * NG + gb] = o;
    }
}

// ---------------------------------------------------------------------------
// Layer-1 LSTM over a chunk: gates = xg1[b,t,:] + h @ w_hh1^T
// ---------------------------------------------------------------------------
__global__ __launch_bounds__(512, 2)
void lstm1_chunk(const float* __restrict__ xg,   // [NB][Tc][NG]
                 const float* __restrict__ w_hh,
                 float* __restrict__ h_state, float* __restrict__ c_state,
                 int Tc, int first)
{
    __shared__ __align__(16) float h_lds[2][NH];
    __shared__ float act_lds[2][NG];

    const int tid = threadIdx.x;
    const int g   = tid;
    const int blk = blockIdx.x;

    float4 w4[32];
    const float4* wp = (const float4*)(w_hh + (size_t)g * NH);
#pragma unroll
    for (int q = 0; q < 32; ++q) w4[q] = wp[q];

    float c_reg = 0.0f, h_keep = 0.0f;
    if (tid < 256) {
        int bb = tid >> 7, j = tid & 127;
        int b  = blk + bb * 256;
        float h = 0.0f;
        if (!first) { h = h_state[b * NH + j]; c_reg = c_state[b * NH + j]; }
        h_lds[bb][j] = h;
        h_keep = h;
    }

    const size_t base0 = ((size_t)blk * Tc) * NG + g;
    const size_t base1 = ((size_t)(blk + 256) * Tc) * NG + g;

    for (int tl = 0; tl < Tc; ++tl) {
        float xg0 = xg[base0 + (size_t)tl * NG];
        float xg1v = xg[base1 + (size_t)tl * NG];
        __syncthreads();   // orders prev update h_lds writes vs dot reads

        float p0a = xg0, p0b = 0.f, p1a = xg1v, p1b = 0.f;
        const float4* h40 = (const float4*)h_lds[0];
        const float4* h41 = (const float4*)h_lds[1];
#pragma unroll
        for (int q = 0; q < 32; ++q) {
            float4 h0v = h40[q], h1v = h41[q], w = w4[q];
            p0a += w.x * h0v.x + w.y * h0v.y;  p0b += w.z * h0v.z + w.w * h0v.w;
            p1a += w.x * h1v.x + w.y * h1v.y;  p1b += w.z * h1v.z + w.w * h1v.w;
        }
        act_lds[0][g] = gate_act(p0a + p0b, g);
        act_lds[1][g] = gate_act(p1a + p1b, g);
        __syncthreads();

        if (tid < 256) {
            int bb = tid >> 7, j = tid & 127;
            float gi = act_lds[bb][j];
            float gf = act_lds[bb][j + 128];
            float gg = act_lds[bb][j + 256];
            float go = act_lds[bb][j + 384];
            c_reg = gf * c_reg + gi * gg;
            float hn = go * fast_tanh(c_reg);
            h_lds[bb][j] = hn;
            h_keep = hn;
        }
    }

    if (tid < 256) {
        int bb = tid >> 7, j = tid & 127;
        int b  = blk + bb * 256;
        h_state[b * NH + j] = h_keep;
        c_state[b * NH + j] = c_reg;
    }
}

// ---------------------------------------------------------------------------
// out[b] = fc2_w . relu(fc1_w @ h1_last[b] + fc1_b) + fc2_b
// one wave per batch row; lane j owns fc1 row j (H2 = 64 = wave size)
// ---------------------------------------------------------------------------
__global__ void fc_head(const float* __restrict__ h1,
                        const float* __restrict__ fc1w, const float* __restrict__ fc1b,
                        const float* __restrict__ fc2w, const float* __restrict__ fc2b,
                        float* __restrict__ out)
{
    int b = blockIdx.x, j = threadIdx.x;
    const float4* wr = (const float4*)(fc1w + (size_t)j * NH);
    const float4* hv = (const float4*)(h1 + (size_t)b * NH);
    float acc = fc1b[j];
#pragma unroll
    for (int q = 0; q < 32; ++q) {
        float4 w = wr[q], h = hv[q];
        acc += w.x * h.x + w.y * h.y + w.z * h.z + w.w * h.w;
    }
    float z = fmaxf(acc, 0.0f);
    float p = fc2w[j] * z;
#pragma unroll
    for (int off = 32; off > 0; off >>= 1) p += __shfl_down(p, off);
    if (j == 0) out[b] = p + fc2b[0];
}

extern "C" void kernel_launch(void* const* d_in, const int* in_sizes, int n_in,
                              void* d_out, int out_size, void* d_ws, size_t ws_size,
                              hipStream_t stream)
{
    const float* x     = (const float*)d_in[0];
    const float* w_ih0 = (const float*)d_in[1];
    const float* w_hh0 = (const float*)d_in[2];
    const float* b_ih0 = (const float*)d_in[3];
    const float* b_hh0 = (const float*)d_in[4];
    const float* w_ih1 = (const float*)d_in[5];
    const float* w_hh1 = (const float*)d_in[6];
    const float* b_ih1 = (const float*)d_in[7];
    const float* b_hh1 = (const float*)d_in[8];
    const float* fc1w  = (const float*)d_in[9];
    const float* fc1b  = (const float*)d_in[10];
    const float* fc2w  = (const float*)d_in[11];
    const float* fc2b  = (const float*)d_in[12];
    float* out = (float*)d_out;
    float* ws  = (float*)d_ws;

    // pick largest time-chunk whose buffers fit in the workspace
    int Tc = 1;
    for (int cand = 256; cand >= 1; cand >>= 1) {
        size_t need = 4ull * ((size_t)NB * cand * (NH + NG) + 4ull * NB * NH);
        if (need <= ws_size) { Tc = cand; break; }
    }

    size_t o_h0  = 0;
    size_t o_xg  = o_h0 + (size_t)NB * Tc * NH;
    size_t o_h0s = o_xg + (size_t)NB * Tc * NG;
    size_t o_c0s = o_h0s + (size_t)NB * NH;
    size_t o_h1s = o_c0s + (size_t)NB * NH;
    size_t o_c1s = o_h1s + (size_t)NB * NH;

    const int M = NB * Tc;
    const int nchunk = NT / Tc;
    for (int c = 0; c < nchunk; ++c) {
        lstm0_chunk<<<256, 512, 0, stream>>>(x, w_ih0, w_hh0, b_ih0, b_hh0,
                                             ws + o_h0, ws + o_h0s, ws + o_c0s,
                                             c * Tc, Tc, c == 0);
        xg_gemm<<<dim3(M / 64, NG / 64), 256, 0, stream>>>(ws + o_h0, w_ih1,
                                                           b_ih1, b_hh1,
                                                           ws + o_xg, M);
        lstm1_chunk<<<256, 512, 0, stream>>>(ws + o_xg, w_hh1,
                                             ws + o_h1s, ws + o_c1s,
                                             Tc, c == 0);
    }
    fc_head<<<NB, 64, 0, stream>>>(ws + o_h1s, fc1w, fc1b, fc2w, fc2b, out);
}

// Round 2
// 2643.974 us; speedup vs baseline: 1.8180x; 1.8180x over previous
//
#include <hip/hip_runtime.h>

#define NB 512
#define NT 256
#define NI 32
#define NH 128
#define NG 512

__device__ __forceinline__ float fsig(float x) { return 1.0f / (1.0f + __expf(-x)); }
__device__ __forceinline__ float ftanh(float x) {
    float ax = fabsf(x);
    float e  = __expf(-2.0f * ax);
    float t  = (1.0f - e) / (1.0f + e);
    return copysignf(t, x);
}

// ---------------------------------------------------------------------------
// Fused LSTM recurrence. 256 blocks x 1024 threads; block owns batches
// {blk, blk+256} for the whole chunk.
//   thread: j = wid*8 + (lane&7)  (hidden unit, 0..127)
//           s = (lane>>3)&7       (k-slice, 0..7)
//   G=4 gate types per thread, Kt = KS per slice.
// LAYER0: virtual K=160 = [h(128) | x(32)], biases added here. x staged into
//         LDS each step by tid<64. KS=20, identity LDS layout (stride 20 hits
//         all 32 banks across slices -> conflict-free b128 reads).
// LAYER1: K=128, KS=16 padded to stride 20; gate preacts xg (bias included)
//         read from global (prefetched at loop top, consumed after butterfly).
// Split-K reduced with 3 shfl_xor over lane bits 3..5; lane s==0 does the
// c/h update. h double-buffered in LDS -> single barrier per step.
// 1024 threads => hard 128-VGPR cap; w-regs are 80 (L0) / 64 (L1).
// ---------------------------------------------------------------------------
template<bool LAYER0>
__global__ __launch_bounds__(1024, 4)
void recur(const float* __restrict__ xin,   // L0: x [NB][NT][NI]; L1: xg [NB][Tc][NG]
           const float* __restrict__ w_hh,  // [NG][NH]
           const float* __restrict__ w_ih,  // L0 only [NG][NI]
           const float* __restrict__ b_ih,  // L0 only
           const float* __restrict__ b_hh,  // L0 only
           float* __restrict__ hout,        // L0: [NB][Tc][NH]; L1: unused
           float* __restrict__ h_state, float* __restrict__ c_state, // [NB][NH]
           int t0, int Tc, int first)
{
    constexpr int KS = LAYER0 ? 20 : 16;
    __shared__ float hx[2][2][160];

    const int tid  = threadIdx.x;
    const int lane = tid & 63;
    const int wid  = tid >> 6;
    const int jLo  = lane & 7;
    const int s    = lane >> 3;
    const int j    = wid * 8 + jLo;
    const int blk  = blockIdx.x;
    const bool wr  = (s == 0);
    const int pos_j = LAYER0 ? j : ((j >> 4) * 20 + (j & 15));

    // persistent weights: w4[type][q] -> 4*KS floats
    float4 w4[4][KS / 4];
#pragma unroll
    for (int t4 = 0; t4 < 4; ++t4) {
        const int g = t4 * NH + j;
#pragma unroll
        for (int q = 0; q < KS / 4; ++q) {
            float4 v;
#pragma unroll
            for (int i = 0; i < 4; ++i) {
                int kk = s * KS + q * 4 + i;
                float f;
                if (LAYER0) f = (kk < NH) ? w_hh[(size_t)g * NH + kk]
                                          : w_ih[(size_t)g * NI + (kk - NH)];
                else        f = w_hh[(size_t)g * NH + kk];
                ((float*)&v)[i] = f;
            }
            w4[t4][q] = v;
        }
    }

    float bias[4];
    if (LAYER0) {
#pragma unroll
        for (int t4 = 0; t4 < 4; ++t4)
            bias[t4] = b_ih[t4 * NH + j] + b_hh[t4 * NH + j];
    }

    float c[2] = {0.f, 0.f};
    if (wr && !first) {
#pragma unroll
        for (int bb = 0; bb < 2; ++bb)
            c[bb] = c_state[(size_t)(blk + bb * 256) * NH + j];
    }

    // stage initial h (and x[t0]) into buffer 0
    if (tid < 256) {
        int bb = tid >> 7, jj = tid & 127;
        float h = first ? 0.f : h_state[(size_t)(blk + bb * 256) * NH + jj];
        int pp = LAYER0 ? jj : ((jj >> 4) * 20 + (jj & 15));
        hx[0][bb][pp] = h;
    }
    if (LAYER0 && tid < 64) {
        int bb = tid >> 5, i = tid & 31;
        hx[0][bb][128 + i] = xin[((size_t)(blk + bb * 256) * NT + t0) * NI + i];
    }
    __syncthreads();

    for (int tl = 0; tl < Tc; ++tl) {
        const int buf = tl & 1, nbuf = buf ^ 1;

        // prefetches (consumed after the dot/butterfly)
        float xpre = 0.f;
        float xg4[4][2];
        if (LAYER0) {
            if (tid < 64) {
                int bb = tid >> 5, i = tid & 31;
                int tn = t0 + tl + 1; if (tn > NT - 1) tn = NT - 1;
                xpre = xin[((size_t)(blk + bb * 256) * NT + tn) * NI + i];
            }
        } else {
            if (wr) {
#pragma unroll
                for (int t4 = 0; t4 < 4; ++t4)
#pragma unroll
                    for (int bb = 0; bb < 2; ++bb)
                        xg4[t4][bb] = xin[((size_t)(blk + bb * 256) * Tc + tl) * NG
                                          + t4 * NH + j];
            }
        }

        // dot over this thread's k-slice, both batches
        float p[4][2] = {};
#pragma unroll
        for (int bb = 0; bb < 2; ++bb) {
            const float4* h4 = (const float4*)(hx[buf][bb] + s * 20);
#pragma unroll
            for (int q = 0; q < KS / 4; ++q) {
                float4 hv = h4[q];
#pragma unroll
                for (int t4 = 0; t4 < 4; ++t4) {
                    float4 w = w4[t4][q];
                    p[t4][bb] += w.x * hv.x + w.y * hv.y + w.z * hv.z + w.w * hv.w;
                }
            }
        }

        // reduce across the 8 k-slices (lane bits 3..5)
#pragma unroll
        for (int t4 = 0; t4 < 4; ++t4)
#pragma unroll
            for (int bb = 0; bb < 2; ++bb) {
                float v = p[t4][bb];
                v += __shfl_xor(v, 8);
                v += __shfl_xor(v, 16);
                v += __shfl_xor(v, 32);
                p[t4][bb] = v;
            }

        // update (slice-0 lanes own unit j)
        if (wr) {
#pragma unroll
            for (int bb = 0; bb < 2; ++bb) {
                float gi, gf, gg, go;
                if (LAYER0) {
                    gi = fsig (p[0][bb] + bias[0]);
                    gf = fsig (p[1][bb] + bias[1]);
                    gg = ftanh(p[2][bb] + bias[2]);
                    go = fsig (p[3][bb] + bias[3]);
                } else {
                    gi = fsig (p[0][bb] + xg4[0][bb]);
                    gf = fsig (p[1][bb] + xg4[1][bb]);
                    gg = ftanh(p[2][bb] + xg4[2][bb]);
                    go = fsig (p[3][bb] + xg4[3][bb]);
                }
                c[bb] = gf * c[bb] + gi * gg;
                float hn = go * ftanh(c[bb]);
                hx[nbuf][bb][pos_j] = hn;
                if (LAYER0)
                    hout[((size_t)(blk + bb * 256) * Tc + tl) * NH + j] = hn;
            }
        }
        if (LAYER0 && tid < 64) {
            int bb = tid >> 5, i = tid & 31;
            hx[nbuf][bb][128 + i] = xpre;
        }
        __syncthreads();
    }

    if (wr) {
        const int bufF = Tc & 1;
#pragma unroll
        for (int bb = 0; bb < 2; ++bb) {
            h_state[(size_t)(blk + bb * 256) * NH + j] = hx[bufF][bb][pos_j];
            c_state[(size_t)(blk + bb * 256) * NH + j] = c[bb];
        }
    }
}

// ---------------------------------------------------------------------------
// xg1 = h0 @ w_ih1^T + (b_ih1 + b_hh1)
// A [M][128], Bw [512][128], C [M][512]. 128x128 tile, 8x8 micro (split
// lo/hi 4-frags at +64 to keep LDS reads <=2-way), K staged in 4 passes of 32.
// ---------------------------------------------------------------------------
__global__ __launch_bounds__(256, 4)
void gemm_xg(const float* __restrict__ A,
             const float* __restrict__ Bw,
             const float* __restrict__ bi, const float* __restrict__ bh,
             float* __restrict__ C, int M)
{
    __shared__ float As[32][132];
    __shared__ float Bs[32][132];
    const int tid = threadIdx.x;
    const int m0 = blockIdx.x * 128;
    const int n0 = blockIdx.y * 128;
    const int tx = tid & 15, ty = tid >> 4;

    float acc[2][2][4][4] = {};

    for (int kp = 0; kp < 4; ++kp) {
        if (kp) __syncthreads();
#pragma unroll
        for (int r = 0; r < 4; ++r) {
            int lin = tid + 256 * r;
            int row = lin >> 3, q = lin & 7;
            float4 va = *(const float4*)&A [(size_t)(m0 + row) * 128 + kp * 32 + q * 4];
            float4 vb = *(const float4*)&Bw[(size_t)(n0 + row) * 128 + kp * 32 + q * 4];
            int k = q * 4;
            As[k + 0][row] = va.x; As[k + 1][row] = va.y;
            As[k + 2][row] = va.z; As[k + 3][row] = va.w;
            Bs[k + 0][row] = vb.x; Bs[k + 1][row] = vb.y;
            Bs[k + 2][row] = vb.z; Bs[k + 3][row] = vb.w;
        }
        __syncthreads();
#pragma unroll
        for (int k = 0; k < 32; ++k) {
            float4 af[2], bf[2];
            af[0] = *(const float4*)&As[k][ty * 4];
            af[1] = *(const float4*)&As[k][64 + ty * 4];
            bf[0] = *(const float4*)&Bs[k][tx * 4];
            bf[1] = *(const float4*)&Bs[k][64 + tx * 4];
#pragma unroll
            for (int ah = 0; ah < 2; ++ah)
#pragma unroll
                for (int bh2 = 0; bh2 < 2; ++bh2) {
                    const float* av = (const float*)&af[ah];
                    const float* bv = (const float*)&bf[bh2];
#pragma unroll
                    for (int i = 0; i < 4; ++i)
#pragma unroll
                        for (int jj = 0; jj < 4; ++jj)
                            acc[ah][bh2][i][jj] += av[i] * bv[jj];
                }
        }
    }

#pragma unroll
    for (int bh2 = 0; bh2 < 2; ++bh2) {
        int n = n0 + bh2 * 64 + tx * 4;
        float4 bias;
        bias.x = bi[n + 0] + bh[n + 0];
        bias.y = bi[n + 1] + bh[n + 1];
        bias.z = bi[n + 2] + bh[n + 2];
        bias.w = bi[n + 3] + bh[n + 3];
#pragma unroll
        for (int ah = 0; ah < 2; ++ah)
#pragma unroll
            for (int i = 0; i < 4; ++i) {
                int m = m0 + ah * 64 + ty * 4 + i;
                float4 o;
                o.x = acc[ah][bh2][i][0] + bias.x;
                o.y = acc[ah][bh2][i][1] + bias.y;
                o.z = acc[ah][bh2][i][2] + bias.z;
                o.w = acc[ah][bh2][i][3] + bias.w;
                *(float4*)&C[(size_t)m * NG + n] = o;
            }
    }
}

// ---------------------------------------------------------------------------
// out[b] = fc2_w . relu(fc1_w @ h1_last[b] + fc1_b) + fc2_b
// ---------------------------------------------------------------------------
__global__ void fc_head(const float* __restrict__ h1,
                        const float* __restrict__ fc1w, const float* __restrict__ fc1b,
                        const float* __restrict__ fc2w, const float* __restrict__ fc2b,
                        float* __restrict__ out)
{
    int b = blockIdx.x, j = threadIdx.x;
    const float4* wr = (const float4*)(fc1w + (size_t)j * NH);
    const float4* hv = (const float4*)(h1 + (size_t)b * NH);
    float acc = fc1b[j];
#pragma unroll
    for (int q = 0; q < 32; ++q) {
        float4 w = wr[q], h = hv[q];
        acc += w.x * h.x + w.y * h.y + w.z * h.z + w.w * h.w;
    }
    float z = fmaxf(acc, 0.0f);
    float p = fc2w[j] * z;
#pragma unroll
    for (int off = 32; off > 0; off >>= 1) p += __shfl_down(p, off);
    if (j == 0) out[b] = p + fc2b[0];
}

extern "C" void kernel_launch(void* const* d_in, const int* in_sizes, int n_in,
                              void* d_out, int out_size, void* d_ws, size_t ws_size,
                              hipStream_t stream)
{
    const float* x     = (const float*)d_in[0];
    const float* w_ih0 = (const float*)d_in[1];
    const float* w_hh0 = (const float*)d_in[2];
    const float* b_ih0 = (const float*)d_in[3];
    const float* b_hh0 = (const float*)d_in[4];
    const float* w_ih1 = (const float*)d_in[5];
    const float* w_hh1 = (const float*)d_in[6];
    const float* b_ih1 = (const float*)d_in[7];
    const float* b_hh1 = (const float*)d_in[8];
    const float* fc1w  = (const float*)d_in[9];
    const float* fc1b  = (const float*)d_in[10];
    const float* fc2w  = (const float*)d_in[11];
    const float* fc2b  = (const float*)d_in[12];
    float* out = (float*)d_out;
    float* ws  = (float*)d_ws;

    // largest power-of-2 chunk whose buffers fit the workspace:
    // h0 [NB][Tc][NH] + xg1 [NB][Tc][NG] + 4 state arrays [NB][NH]
    int Tc = 1;
    for (int cand = 256; cand >= 1; cand >>= 1) {
        size_t need = 4ull * ((size_t)NB * cand * (NH + NG) + 4ull * NB * NH);
        if (need <= ws_size) { Tc = cand; break; }
    }

    size_t o_h0  = 0;
    size_t o_xg  = o_h0 + (size_t)NB * Tc * NH;
    size_t o_h0s = o_xg + (size_t)NB * Tc * NG;
    size_t o_c0s = o_h0s + (size_t)NB * NH;
    size_t o_h1s = o_c0s + (size_t)NB * NH;
    size_t o_c1s = o_h1s + (size_t)NB * NH;

    const int M = NB * Tc;
    const int nchunk = NT / Tc;
    for (int c = 0; c < nchunk; ++c) {
        recur<true><<<256, 1024, 0, stream>>>(x, w_hh0, w_ih0, b_ih0, b_hh0,
                                              ws + o_h0, ws + o_h0s, ws + o_c0s,
                                              c * Tc, Tc, c == 0);
        gemm_xg<<<dim3(M / 128, 4), 256, 0, stream>>>(ws + o_h0, w_ih1,
                                                      b_ih1, b_hh1,
                                                      ws + o_xg, M);
        recur<false><<<256, 1024, 0, stream>>>(ws + o_xg, w_hh1, nullptr,
                                               nullptr, nullptr,
                                               nullptr, ws + o_h1s, ws + o_c1s,
                                               0, Tc, c == 0);
    }
    fc_head<<<NB, 64, 0, stream>>>(ws + o_h1s, fc1w, fc1b, fc2w, fc2b, out);
}

// Round 3
// 1998.603 us; speedup vs baseline: 2.4050x; 1.3229x over previous
//
#include <hip/hip_runtime.h>

#define NB 512
#define NT 256
#define NI 32
#define NH 128
#define NG 512

__device__ __forceinline__ float fsig(float x) { return 1.0f / (1.0f + __expf(-x)); }
__device__ __forceinline__ float ftanh(float x) {
    float ax = fabsf(x);
    float e  = __expf(-2.0f * ax);
    float t  = (1.0f - e) / (1.0f + e);
    return copysignf(t, x);
}

// ---------------------------------------------------------------------------
// Fused LSTM recurrence. 256 blocks x 1024 threads; block owns batches
// {blk, blk+256} for the whole chunk.
//   thread: j = wid*8 + (lane&7)  (hidden unit, 0..127)
//           s = (lane>>3)&7       (k-slice, 0..7)
//   4 gate types per thread, KS k-values per slice.
// LAYER0: virtual K=160 = [h(128) | x(32)], biases added here. KS=20.
// LAYER1: K=128, KS=16, h stored padded to stride 20 (slices disjoint across
//         all 32 banks -> conflict-free b128 reads, verified 0 conflicts).
// Split-K reduced with 3 shfl_xor over lane bits 3..5; s==0 lanes update c/h.
// Double-buffered h in LDS -> single barrier per step.
//
// __launch_bounds__(1024, 1): on this ROCm the 2nd arg behaves like CUDA's
// MIN_BLOCKS_PER_CU (R1/R2 evidence: (512,2)->128 VGPR, (1024,4)->64 VGPR).
// 1 block/CU -> 4 waves/SIMD -> 128-VGPR cap; weight arrays (80/64 floats)
// stay in registers. (1024,4) caused a 1.6 GB/dispatch scratch-spill leak.
// ---------------------------------------------------------------------------
template<bool LAYER0>
__global__ __launch_bounds__(1024, 1)
void recur(const float* __restrict__ xin,   // L0: x [NB][NT][NI]; L1: xg [NB][Tc][NG]
           const float* __restrict__ w_hh,  // [NG][NH]
           const float* __restrict__ w_ih,  // L0 only [NG][NI]
           const float* __restrict__ b_ih,  // L0 only
           const float* __restrict__ b_hh,  // L0 only
           float* __restrict__ hout,        // L0: [NB][Tc][NH]; L1: unused
           float* __restrict__ h_state, float* __restrict__ c_state, // [NB][NH]
           int t0, int Tc, int first)
{
    constexpr int KS = LAYER0 ? 20 : 16;
    __shared__ float hx[2][2][160];

    const int tid  = threadIdx.x;
    const int lane = tid & 63;
    const int wid  = tid >> 6;
    const int jLo  = lane & 7;
    const int s    = lane >> 3;
    const int j    = wid * 8 + jLo;
    const int blk  = blockIdx.x;
    const bool wr  = (s == 0);
    const int pos_j = LAYER0 ? j : ((j >> 4) * 20 + (j & 15));

    // persistent weights: w4[type][q] -> 4*KS floats per thread
    float4 w4[4][KS / 4];
#pragma unroll
    for (int t4 = 0; t4 < 4; ++t4) {
        const int g = t4 * NH + j;
#pragma unroll
        for (int q = 0; q < KS / 4; ++q) {
            float4 v;
#pragma unroll
            for (int i = 0; i < 4; ++i) {
                int kk = s * KS + q * 4 + i;
                float f;
                if (LAYER0) f = (kk < NH) ? w_hh[(size_t)g * NH + kk]
                                          : w_ih[(size_t)g * NI + (kk - NH)];
                else        f = w_hh[(size_t)g * NH + kk];
                ((float*)&v)[i] = f;
            }
            w4[t4][q] = v;
        }
    }

    float bias[4];
    if (LAYER0) {
#pragma unroll
        for (int t4 = 0; t4 < 4; ++t4)
            bias[t4] = b_ih[t4 * NH + j] + b_hh[t4 * NH + j];
    }

    float c[2] = {0.f, 0.f};
    if (wr && !first) {
#pragma unroll
        for (int bb = 0; bb < 2; ++bb)
            c[bb] = c_state[(size_t)(blk + bb * 256) * NH + j];
    }

    // stage initial h (and x[t0]) into buffer 0
    if (tid < 256) {
        int bb = tid >> 7, jj = tid & 127;
        float h = first ? 0.f : h_state[(size_t)(blk + bb * 256) * NH + jj];
        int pp = LAYER0 ? jj : ((jj >> 4) * 20 + (jj & 15));
        hx[0][bb][pp] = h;
    }
    if (LAYER0 && tid < 64) {
        int bb = tid >> 5, i = tid & 31;
        hx[0][bb][128 + i] = xin[((size_t)(blk + bb * 256) * NT + t0) * NI + i];
    }
    __syncthreads();

    for (int tl = 0; tl < Tc; ++tl) {
        const int buf = tl & 1, nbuf = buf ^ 1;

        // prefetches (consumed after the dot/butterfly)
        float xpre = 0.f;
        float xg4[4][2];
        if (LAYER0) {
            if (tid < 64) {
                int bb = tid >> 5, i = tid & 31;
                int tn = t0 + tl + 1; if (tn > NT - 1) tn = NT - 1;
                xpre = xin[((size_t)(blk + bb * 256) * NT + tn) * NI + i];
            }
        } else {
            if (wr) {
#pragma unroll
                for (int t4 = 0; t4 < 4; ++t4)
#pragma unroll
                    for (int bb = 0; bb < 2; ++bb)
                        xg4[t4][bb] = xin[((size_t)(blk + bb * 256) * Tc + tl) * NG
                                          + t4 * NH + j];
            }
        }

        // dot over this thread's k-slice, both batches
        float p[4][2] = {};
        {
            const float4* h40 = (const float4*)(hx[buf][0] + s * 20);
            const float4* h41 = (const float4*)(hx[buf][1] + s * 20);
#pragma unroll
            for (int q = 0; q < KS / 4; ++q) {
                float4 hv0 = h40[q];
                float4 hv1 = h41[q];
#pragma unroll
                for (int t4 = 0; t4 < 4; ++t4) {
                    float4 w = w4[t4][q];
                    p[t4][0] += w.x * hv0.x + w.y * hv0.y + w.z * hv0.z + w.w * hv0.w;
                    p[t4][1] += w.x * hv1.x + w.y * hv1.y + w.z * hv1.z + w.w * hv1.w;
                }
            }
        }

        // reduce across the 8 k-slices (lane bits 3..5)
#pragma unroll
        for (int t4 = 0; t4 < 4; ++t4)
#pragma unroll
            for (int bb = 0; bb < 2; ++bb) {
                float v = p[t4][bb];
                v += __shfl_xor(v, 8);
                v += __shfl_xor(v, 16);
                v += __shfl_xor(v, 32);
                p[t4][bb] = v;
            }

        // update (slice-0 lanes own unit j)
        if (wr) {
#pragma unroll
            for (int bb = 0; bb < 2; ++bb) {
                float gi, gf, gg, go;
                if (LAYER0) {
                    gi = fsig (p[0][bb] + bias[0]);
                    gf = fsig (p[1][bb] + bias[1]);
                    gg = ftanh(p[2][bb] + bias[2]);
                    go = fsig (p[3][bb] + bias[3]);
                } else {
                    gi = fsig (p[0][bb] + xg4[0][bb]);
                    gf = fsig (p[1][bb] + xg4[1][bb]);
                    gg = ftanh(p[2][bb] + xg4[2][bb]);
                    go = fsig (p[3][bb] + xg4[3][bb]);
                }
                c[bb] = gf * c[bb] + gi * gg;
                float hn = go * ftanh(c[bb]);
                hx[nbuf][bb][pos_j] = hn;
                if (LAYER0)
                    hout[((size_t)(blk + bb * 256) * Tc + tl) * NH + j] = hn;
            }
        }
        if (LAYER0 && tid < 64) {
            int bb = tid >> 5, i = tid & 31;
            hx[nbuf][bb][128 + i] = xpre;
        }
        __syncthreads();
    }

    if (wr) {
        const int bufF = Tc & 1;
#pragma unroll
        for (int bb = 0; bb < 2; ++bb) {
            h_state[(size_t)(blk + bb * 256) * NH + j] = hx[bufF][bb][pos_j];
            c_state[(size_t)(blk + bb * 256) * NH + j] = c[bb];
        }
    }
}

// ---------------------------------------------------------------------------
// xg1 = h0 @ w_ih1^T + (b_ih1 + b_hh1)
// A [M][128], Bw [512][128], C [M][512]. 128x128 tile, 8x8 micro (split
// lo/hi 4-frags at +64), K staged in 4 passes of 32.
// ---------------------------------------------------------------------------
__global__ __launch_bounds__(256, 4)
void gemm_xg(const float* __restrict__ A,
             const float* __restrict__ Bw,
             const float* __restrict__ bi, const float* __restrict__ bh,
             float* __restrict__ C, int M)
{
    __shared__ float As[32][132];
    __shared__ float Bs[32][132];
    const int tid = threadIdx.x;
    const int m0 = blockIdx.x * 128;
    const int n0 = blockIdx.y * 128;
    const int tx = tid & 15, ty = tid >> 4;

    float acc[2][2][4][4] = {};

    for (int kp = 0; kp < 4; ++kp) {
        if (kp) __syncthreads();
#pragma unroll
        for (int r = 0; r < 4; ++r) {
            int lin = tid + 256 * r;
            int row = lin >> 3, q = lin & 7;
            float4 va = *(const float4*)&A [(size_t)(m0 + row) * 128 + kp * 32 + q * 4];
            float4 vb = *(const float4*)&Bw[(size_t)(n0 + row) * 128 + kp * 32 + q * 4];
            int k = q * 4;
            As[k + 0][row] = va.x; As[k + 1][row] = va.y;
            As[k + 2][row] = va.z; As[k + 3][row] = va.w;
            Bs[k + 0][row] = vb.x; Bs[k + 1][row] = vb.y;
            Bs[k + 2][row] = vb.z; Bs[k + 3][row] = vb.w;
        }
        __syncthreads();
#pragma unroll
        for (int k = 0; k < 32; ++k) {
            float4 af[2], bf[2];
            af[0] = *(const float4*)&As[k][ty * 4];
            af[1] = *(const float4*)&As[k][64 + ty * 4];
            bf[0] = *(const float4*)&Bs[k][tx * 4];
            bf[1] = *(const float4*)&Bs[k][64 + tx * 4];
#pragma unroll
            for (int ah = 0; ah < 2; ++ah)
#pragma unroll
                for (int bh2 = 0; bh2 < 2; ++bh2) {
                    const float* av = (const float*)&af[ah];
                    const float* bv = (const float*)&bf[bh2];
#pragma unroll
                    for (int i = 0; i < 4; ++i)
#pragma unroll
                        for (int jj = 0; jj < 4; ++jj)
                            acc[ah][bh2][i][jj] += av[i] * bv[jj];
                }
        }
    }

#pragma unroll
    for (int bh2 = 0; bh2 < 2; ++bh2) {
        int n = n0 + bh2 * 64 + tx * 4;
        float4 bias;
        bias.x = bi[n + 0] + bh[n + 0];
        bias.y = bi[n + 1] + bh[n + 1];
        bias.z = bi[n + 2] + bh[n + 2];
        bias.w = bi[n + 3] + bh[n + 3];
#pragma unroll
        for (int ah = 0; ah < 2; ++ah)
#pragma unroll
            for (int i = 0; i < 4; ++i) {
                int m = m0 + ah * 64 + ty * 4 + i;
                float4 o;
                o.x = acc[ah][bh2][i][0] + bias.x;
                o.y = acc[ah][bh2][i][1] + bias.y;
                o.z = acc[ah][bh2][i][2] + bias.z;
                o.w = acc[ah][bh2][i][3] + bias.w;
                *(float4*)&C[(size_t)m * NG + n] = o;
            }
    }
}

// ---------------------------------------------------------------------------
// out[b] = fc2_w . relu(fc1_w @ h1_last[b] + fc1_b) + fc2_b
// ---------------------------------------------------------------------------
__global__ void fc_head(const float* __restrict__ h1,
                        const float* __restrict__ fc1w, const float* __restrict__ fc1b,
                        const float* __restrict__ fc2w, const float* __restrict__ fc2b,
                        float* __restrict__ out)
{
    int b = blockIdx.x, j = threadIdx.x;
    const float4* wr = (const float4*)(fc1w + (size_t)j * NH);
    const float4* hv = (const float4*)(h1 + (size_t)b * NH);
    float acc = fc1b[j];
#pragma unroll
    for (int q = 0; q < 32; ++q) {
        float4 w = wr[q], h = hv[q];
        acc += w.x * h.x + w.y * h.y + w.z * h.z + w.w * h.w;
    }
    float z = fmaxf(acc, 0.0f);
    float p = fc2w[j] * z;
#pragma unroll
    for (int off = 32; off > 0; off >>= 1) p += __shfl_down(p, off);
    if (j == 0) out[b] = p + fc2b[0];
}

extern "C" void kernel_launch(void* const* d_in, const int* in_sizes, int n_in,
                              void* d_out, int out_size, void* d_ws, size_t ws_size,
                              hipStream_t stream)
{
    const float* x     = (const float*)d_in[0];
    const float* w_ih0 = (const float*)d_in[1];
    const float* w_hh0 = (const float*)d_in[2];
    const float* b_ih0 = (const float*)d_in[3];
    const float* b_hh0 = (const float*)d_in[4];
    const float* w_ih1 = (const float*)d_in[5];
    const float* w_hh1 = (const float*)d_in[6];
    const float* b_ih1 = (const float*)d_in[7];
    const float* b_hh1 = (const float*)d_in[8];
    const float* fc1w  = (const float*)d_in[9];
    const float* fc1b  = (const float*)d_in[10];
    const float* fc2w  = (const float*)d_in[11];
    const float* fc2b  = (const float*)d_in[12];
    float* out = (float*)d_out;
    float* ws  = (float*)d_ws;

    // largest power-of-2 chunk whose buffers fit the workspace
    int Tc = 1;
    for (int cand = 256; cand >= 1; cand >>= 1) {
        size_t need = 4ull * ((size_t)NB * cand * (NH + NG) + 4ull * NB * NH);
        if (need <= ws_size) { Tc = cand; break; }
    }

    size_t o_h0  = 0;
    size_t o_xg  = o_h0 + (size_t)NB * Tc * NH;
    size_t o_h0s = o_xg + (size_t)NB * Tc * NG;
    size_t o_c0s = o_h0s + (size_t)NB * NH;
    size_t o_h1s = o_c0s + (size_t)NB * NH;
    size_t o_c1s = o_h1s + (size_t)NB * NH;

    const int M = NB * Tc;
    const int nchunk = NT / Tc;
    for (int c = 0; c < nchunk; ++c) {
        recur<true><<<256, 1024, 0, stream>>>(x, w_hh0, w_ih0, b_ih0, b_hh0,
                                              ws + o_h0, ws + o_h0s, ws + o_c0s,
                                              c * Tc, Tc, c == 0);
        gemm_xg<<<dim3(M / 128, 4), 256, 0, stream>>>(ws + o_h0, w_ih1,
                                                      b_ih1, b_hh1,
                                                      ws + o_xg, M);
        recur<false><<<256, 1024, 0, stream>>>(ws + o_xg, w_hh1, nullptr,
                                               nullptr, nullptr,
                                               nullptr, ws + o_h1s, ws + o_c1s,
                                               0, Tc, c == 0);
    }
    fc_head<<<NB, 64, 0, stream>>>(ws + o_h1s, fc1w, fc1b, fc2w, fc2b, out);
}

// Round 4
// 1996.067 us; speedup vs baseline: 2.4081x; 1.0013x over previous
//
#include <hip/hip_runtime.h>

#define NB 512
#define NT 256
#define NI 32
#define NH 128
#define NG 512

__device__ __forceinline__ float fsig(float x) { return 1.0f / (1.0f + __expf(-x)); }
__device__ __forceinline__ float ftanh(float x) {
    float ax = fabsf(x);
    float e  = __expf(-2.0f * ax);
    float t  = (1.0f - e) / (1.0f + e);
    return copysignf(t, x);
}

// ---------------------------------------------------------------------------
// Fused LSTM recurrence. 256 blocks x 1024 threads; block owns batches
// {blk, blk+256} for the whole chunk.
//   thread: j = wid*8 + (lane&7)  (hidden unit, 0..127)
//           s = (lane>>3)&7       (k-slice, 0..7)
//   4 gate types per thread, KS k-values per slice.
// LAYER0: virtual K=160 = [h(128) | x(32)], biases added here. KS=20.
// LAYER1: K=128, KS=16, h stored padded to stride 20.
// Split-K reduced with 3 shfl_xor over lane bits 3..5; s==0 lanes update c/h.
// Double-buffered h in LDS -> single barrier per step.
//
// Register budget history (the critical lesson of R1-R3):
//   per-thread weight footprint is irreducibly 80 floats (81920/1024);
//   (512,2)->128 VGPR spill, (1024,4)->64 VGPR 1.6GB leak, (1024,1)->still 64.
//   amdgpu_waves_per_eu(4,4) pins allocator budget to 512/4 = 128 VGPRs AND
//   sets the scheduler's occupancy target to exactly 4 waves/EU -> no spill.
// ---------------------------------------------------------------------------
template<bool LAYER0>
__global__ __launch_bounds__(1024)
__attribute__((amdgpu_waves_per_eu(4, 4)))
void recur(const float* __restrict__ xin,   // L0: x [NB][NT][NI]; L1: xg [NB][Tc][NG]
           const float* __restrict__ w_hh,  // [NG][NH]
           const float* __restrict__ w_ih,  // L0 only [NG][NI]
           const float* __restrict__ b_ih,  // L0 only
           const float* __restrict__ b_hh,  // L0 only
           float* __restrict__ hout,        // L0: [NB][Tc][NH]; L1: unused
           float* __restrict__ h_state, float* __restrict__ c_state, // [NB][NH]
           int t0, int Tc, int first)
{
    constexpr int KS = LAYER0 ? 20 : 16;
    __shared__ float hx[2][2][160];

    const int tid  = threadIdx.x;
    const int lane = tid & 63;
    const int wid  = tid >> 6;
    const int jLo  = lane & 7;
    const int s    = lane >> 3;
    const int j    = wid * 8 + jLo;
    const int blk  = blockIdx.x;
    const bool wr  = (s == 0);
    const int pos_j = LAYER0 ? j : ((j >> 4) * 20 + (j & 15));

    // persistent weights: w4[type][q] -> 4*KS floats per thread
    float4 w4[4][KS / 4];
#pragma unroll
    for (int t4 = 0; t4 < 4; ++t4) {
        const int g = t4 * NH + j;
#pragma unroll
        for (int q = 0; q < KS / 4; ++q) {
            float4 v;
#pragma unroll
            for (int i = 0; i < 4; ++i) {
                int kk = s * KS + q * 4 + i;
                float f;
                if (LAYER0) f = (kk < NH) ? w_hh[(size_t)g * NH + kk]
                                          : w_ih[(size_t)g * NI + (kk - NH)];
                else        f = w_hh[(size_t)g * NH + kk];
                ((float*)&v)[i] = f;
            }
            w4[t4][q] = v;
        }
    }

    float bias[4];
    if (LAYER0) {
#pragma unroll
        for (int t4 = 0; t4 < 4; ++t4)
            bias[t4] = b_ih[t4 * NH + j] + b_hh[t4 * NH + j];
    }

    float c[2] = {0.f, 0.f};
    if (wr && !first) {
#pragma unroll
        for (int bb = 0; bb < 2; ++bb)
            c[bb] = c_state[(size_t)(blk + bb * 256) * NH + j];
    }

    // stage initial h (and x[t0]) into buffer 0
    if (tid < 256) {
        int bb = tid >> 7, jj = tid & 127;
        float h = first ? 0.f : h_state[(size_t)(blk + bb * 256) * NH + jj];
        int pp = LAYER0 ? jj : ((jj >> 4) * 20 + (jj & 15));
        hx[0][bb][pp] = h;
    }
    if (LAYER0 && tid < 64) {
        int bb = tid >> 5, i = tid & 31;
        hx[0][bb][128 + i] = xin[((size_t)(blk + bb * 256) * NT + t0) * NI + i];
    }
    __syncthreads();

    for (int tl = 0; tl < Tc; ++tl) {
        const int buf = tl & 1, nbuf = buf ^ 1;

        // prefetches (consumed after the dot/butterfly)
        float xpre = 0.f;
        float xg4[4][2];
        if (LAYER0) {
            if (tid < 64) {
                int bb = tid >> 5, i = tid & 31;
                int tn = t0 + tl + 1; if (tn > NT - 1) tn = NT - 1;
                xpre = xin[((size_t)(blk + bb * 256) * NT + tn) * NI + i];
            }
        } else {
            if (wr) {
#pragma unroll
                for (int t4 = 0; t4 < 4; ++t4)
#pragma unroll
                    for (int bb = 0; bb < 2; ++bb)
                        xg4[t4][bb] = xin[((size_t)(blk + bb * 256) * Tc + tl) * NG
                                          + t4 * NH + j];
            }
        }

        // dot over this thread's k-slice, both batches
        float p[4][2] = {};
        {
            const float4* h40 = (const float4*)(hx[buf][0] + s * 20);
            const float4* h41 = (const float4*)(hx[buf][1] + s * 20);
#pragma unroll
            for (int q = 0; q < KS / 4; ++q) {
                float4 hv0 = h40[q];
                float4 hv1 = h41[q];
#pragma unroll
                for (int t4 = 0; t4 < 4; ++t4) {
                    float4 w = w4[t4][q];
                    p[t4][0] += w.x * hv0.x + w.y * hv0.y + w.z * hv0.z + w.w * hv0.w;
                    p[t4][1] += w.x * hv1.x + w.y * hv1.y + w.z * hv1.z + w.w * hv1.w;
                }
            }
        }

        // reduce across the 8 k-slices (lane bits 3..5)
#pragma unroll
        for (int t4 = 0; t4 < 4; ++t4)
#pragma unroll
            for (int bb = 0; bb < 2; ++bb) {
                float v = p[t4][bb];
                v += __shfl_xor(v, 8);
                v += __shfl_xor(v, 16);
                v += __shfl_xor(v, 32);
                p[t4][bb] = v;
            }

        // update (slice-0 lanes own unit j)
        if (wr) {
#pragma unroll
            for (int bb = 0; bb < 2; ++bb) {
                float gi, gf, gg, go;
                if (LAYER0) {
                    gi = fsig (p[0][bb] + bias[0]);
                    gf = fsig (p[1][bb] + bias[1]);
                    gg = ftanh(p[2][bb] + bias[2]);
                    go = fsig (p[3][bb] + bias[3]);
                } else {
                    gi = fsig (p[0][bb] + xg4[0][bb]);
                    gf = fsig (p[1][bb] + xg4[1][bb]);
                    gg = ftanh(p[2][bb] + xg4[2][bb]);
                    go = fsig (p[3][bb] + xg4[3][bb]);
                }
                c[bb] = gf * c[bb] + gi * gg;
                float hn = go * ftanh(c[bb]);
                hx[nbuf][bb][pos_j] = hn;
                if (LAYER0)
                    hout[((size_t)(blk + bb * 256) * Tc + tl) * NH + j] = hn;
            }
        }
        if (LAYER0 && tid < 64) {
            int bb = tid >> 5, i = tid & 31;
            hx[nbuf][bb][128 + i] = xpre;
        }
        __syncthreads();
    }

    if (wr) {
        const int bufF = Tc & 1;
#pragma unroll
        for (int bb = 0; bb < 2; ++bb) {
            h_state[(size_t)(blk + bb * 256) * NH + j] = hx[bufF][bb][pos_j];
            c_state[(size_t)(blk + bb * 256) * NH + j] = c[bb];
        }
    }
}

// ---------------------------------------------------------------------------
// xg1 = h0 @ w_ih1^T + (b_ih1 + b_hh1)
// A [M][128], Bw [512][128], C [M][512]. 128x128 tile, 8x8 micro (split
// lo/hi 4-frags at +64), K staged in 4 passes of 32.
// ---------------------------------------------------------------------------
__global__ __launch_bounds__(256, 4)
void gemm_xg(const float* __restrict__ A,
             const float* __restrict__ Bw,
             const float* __restrict__ bi, const float* __restrict__ bh,
             float* __restrict__ C, int M)
{
    __shared__ float As[32][132];
    __shared__ float Bs[32][132];
    const int tid = threadIdx.x;
    const int m0 = blockIdx.x * 128;
    const int n0 = blockIdx.y * 128;
    const int tx = tid & 15, ty = tid >> 4;

    float acc[2][2][4][4] = {};

    for (int kp = 0; kp < 4; ++kp) {
        if (kp) __syncthreads();
#pragma unroll
        for (int r = 0; r < 4; ++r) {
            int lin = tid + 256 * r;
            int row = lin >> 3, q = lin & 7;
            float4 va = *(const float4*)&A [(size_t)(m0 + row) * 128 + kp * 32 + q * 4];
            float4 vb = *(const float4*)&Bw[(size_t)(n0 + row) * 128 + kp * 32 + q * 4];
            int k = q * 4;
            As[k + 0][row] = va.x; As[k + 1][row] = va.y;
            As[k + 2][row] = va.z; As[k + 3][row] = va.w;
            Bs[k + 0][row] = vb.x; Bs[k + 1][row] = vb.y;
            Bs[k + 2][row] = vb.z; Bs[k + 3][row] = vb.w;
        }
        __syncthreads();
#pragma unroll
        for (int k = 0; k < 32; ++k) {
            float4 af[2], bf[2];
            af[0] = *(const float4*)&As[k][ty * 4];
            af[1] = *(const float4*)&As[k][64 + ty * 4];
            bf[0] = *(const float4*)&Bs[k][tx * 4];
            bf[1] = *(const float4*)&Bs[k][64 + tx * 4];
#pragma unroll
            for (int ah = 0; ah < 2; ++ah)
#pragma unroll
                for (int bh2 = 0; bh2 < 2; ++bh2) {
                    const float* av = (const float*)&af[ah];
                    const float* bv = (const float*)&bf[bh2];
#pragma unroll
                    for (int i = 0; i < 4; ++i)
#pragma unroll
                        for (int jj = 0; jj < 4; ++jj)
                            acc[ah][bh2][i][jj] += av[i] * bv[jj];
                }
        }
    }

#pragma unroll
    for (int bh2 = 0; bh2 < 2; ++bh2) {
        int n = n0 + bh2 * 64 + tx * 4;
        float4 bias;
        bias.x = bi[n + 0] + bh[n + 0];
        bias.y = bi[n + 1] + bh[n + 1];
        bias.z = bi[n + 2] + bh[n + 2];
        bias.w = bi[n + 3] + bh[n + 3];
#pragma unroll
        for (int ah = 0; ah < 2; ++ah)
#pragma unroll
            for (int i = 0; i < 4; ++i) {
                int m = m0 + ah * 64 + ty * 4 + i;
                float4 o;
                o.x = acc[ah][bh2][i][0] + bias.x;
                o.y = acc[ah][bh2][i][1] + bias.y;
                o.z = acc[ah][bh2][i][2] + bias.z;
                o.w = acc[ah][bh2][i][3] + bias.w;
                *(float4*)&C[(size_t)m * NG + n] = o;
            }
    }
}

// ---------------------------------------------------------------------------
// out[b] = fc2_w . relu(fc1_w @ h1_last[b] + fc1_b) + fc2_b
// ---------------------------------------------------------------------------
__global__ void fc_head(const float* __restrict__ h1,
                        const float* __restrict__ fc1w, const float* __restrict__ fc1b,
                        const float* __restrict__ fc2w, const float* __restrict__ fc2b,
                        float* __restrict__ out)
{
    int b = blockIdx.x, j = threadIdx.x;
    const float4* wr = (const float4*)(fc1w + (size_t)j * NH);
    const float4* hv = (const float4*)(h1 + (size_t)b * NH);
    float acc = fc1b[j];
#pragma unroll
    for (int q = 0; q < 32; ++q) {
        float4 w = wr[q], h = hv[q];
        acc += w.x * h.x + w.y * h.y + w.z * h.z + w.w * h.w;
    }
    float z = fmaxf(acc, 0.0f);
    float p = fc2w[j] * z;
#pragma unroll
    for (int off = 32; off > 0; off >>= 1) p += __shfl_down(p, off);
    if (j == 0) out[b] = p + fc2b[0];
}

extern "C" void kernel_launch(void* const* d_in, const int* in_sizes, int n_in,
                              void* d_out, int out_size, void* d_ws, size_t ws_size,
                              hipStream_t stream)
{
    const float* x     = (const float*)d_in[0];
    const float* w_ih0 = (const float*)d_in[1];
    const float* w_hh0 = (const float*)d_in[2];
    const float* b_ih0 = (const float*)d_in[3];
    const float* b_hh0 = (const float*)d_in[4];
    const float* w_ih1 = (const float*)d_in[5];
    const float* w_hh1 = (const float*)d_in[6];
    const float* b_ih1 = (const float*)d_in[7];
    const float* b_hh1 = (const float*)d_in[8];
    const float* fc1w  = (const float*)d_in[9];
    const float* fc1b  = (const float*)d_in[10];
    const float* fc2w  = (const float*)d_in[11];
    const float* fc2b  = (const float*)d_in[12];
    float* out = (float*)d_out;
    float* ws  = (float*)d_ws;

    // largest power-of-2 chunk whose buffers fit the workspace
    int Tc = 1;
    for (int cand = 256; cand >= 1; cand >>= 1) {
        size_t need = 4ull * ((size_t)NB * cand * (NH + NG) + 4ull * NB * NH);
        if (need <= ws_size) { Tc = cand; break; }
    }

    size_t o_h0  = 0;
    size_t o_xg  = o_h0 + (size_t)NB * Tc * NH;
    size_t o_h0s = o_xg + (size_t)NB * Tc * NG;
    size_t o_c0s = o_h0s + (size_t)NB * NH;
    size_t o_h1s = o_c0s + (size_t)NB * NH;
    size_t o_c1s = o_h1s + (size_t)NB * NH;

    const int M = NB * Tc;
    const int nchunk = NT / Tc;
    for (int c = 0; c < nchunk; ++c) {
        recur<true><<<256, 1024, 0, stream>>>(x, w_hh0, w_ih0, b_ih0, b_hh0,
                                              ws + o_h0, ws + o_h0s, ws + o_c0s,
                                              c * Tc, Tc, c == 0);
        gemm_xg<<<dim3(M / 128, 4), 256, 0, stream>>>(ws + o_h0, w_ih1,
                                                      b_ih1, b_hh1,
                                                      ws + o_xg, M);
        recur<false><<<256, 1024, 0, stream>>>(ws + o_xg, w_hh1, nullptr,
                                               nullptr, nullptr,
                                               nullptr, ws + o_h1s, ws + o_c1s,
                                               0, Tc, c == 0);
    }
    fc_head<<<NB, 64, 0, stream>>>(ws + o_h1s, fc1w, fc1b, fc2w, fc2b, out);
}